// Round 20
// baseline (23.785 us; speedup 1.0000x reference)
//
#include <hip/hip_runtime.h>

// Problem constants (fixed by setup_inputs)
#define K   19
#define C   256
#define HF  64
#define WF  128
#define HW  (HF * WF)
#define BB  4
#define HL  512
#define WL  1024

// bf16-split-x3 distance error bound ~1e-3 worst-case; pixels whose top-2
// gap < TAU get the proven exact-f64 cooperative resolve.
#define TAU 0.03f

#define CPAD 264    // halfwords per centroid row: 528 B = 33 x 16 B
#define DPAD 66     // dwords per acc row

typedef __attribute__((ext_vector_type(8)))  short bf16x8;
typedef __attribute__((ext_vector_type(16))) float f32x16;

// R19 + full-K-per-wave: each wave owns ONE 32-px tile for ALL 256 channels
// (16 K-steps, 48 MFMA) instead of splitting K across wave pairs. Effects:
// (a) 2x the independent load stream per wave (16 fully-unrolled steps) for
//     latency hoisting -- R19's 8-step/wave chain stalled ~50% on first-touch
//     HBM latency at 4 waves/SIMD coverage;
// (b) no kh-merge: dbuf halves, epilogue sum is a single read;
// (c) 128 px/block: centroid staging + c2 amortized 2x, half the blocks;
// (d) epilogue on waves 0+1 (disjoint 64-px domains, R8-proven pattern each).
__global__ __launch_bounds__(256, 4) void centroid_mask_kernel(
    const float* __restrict__ feat0,   // feature_s2t
    const float* __restrict__ feat1,   // feature_target
    const float* __restrict__ cent0,   // centroids for map 0 (centroid_target)
    const float* __restrict__ cent1,   // centroids for map 1 (centroid_s2t)
    int* __restrict__ out)             // [2][BB][HL][WL] int32
{
    __shared__ __align__(16) unsigned short chi[K * CPAD];  // centroid hi bf16
    __shared__ __align__(16) unsigned short clo[K * CPAD];  // centroid lo bf16
    __shared__ float  dbuf[4][16][DPAD];     // [tile][reg][32h+k]
    __shared__ double c2p[K][8];             // exact ||c||^2 partials
    __shared__ double sc2d[K];               // exact ||c||^2 (f64)
    __shared__ float  sc2f[K];               // rounded-exact ||c||^2 (f32)

    const int map = blockIdx.y;
    const float* __restrict__ feat = (map == 0) ? feat0 : feat1;
    const float* __restrict__ cent = (map == 0) ? cent0 : cent1;

    const int tid  = threadIdx.x;
    const int lane = tid & 63;
    const int wv   = __builtin_amdgcn_readfirstlane(tid >> 6);   // 0..3, uniform

    // ---- stage split centroids into LDS (coalesced) + exact ||c||^2 ----
    for (int i = tid; i < K * C; i += 256) {
        const int k = i >> 8, c = i & (C - 1);
        const unsigned u = __float_as_uint(cent[i]);
        const float r = __uint_as_float(u) - __uint_as_float(u & 0xffff0000u);
        chi[k * CPAD + c] = (unsigned short)(u >> 16);
        clo[k * CPAD + c] = (unsigned short)(__float_as_uint(r) >> 16);
    }
    if (tid < K * 8) {
        const int k = tid >> 3, sl = tid & 7;
        const float* cp = cent + k * C + sl * 32;
        double s = 0.0;
        #pragma unroll
        for (int j = 0; j < 32; ++j) { double v = (double)cp[j]; s = fma(v, v, s); }
        c2p[k][sl] = s;
    }
    __syncthreads();
    if (tid < K) {
        double s = 0.0;
        #pragma unroll
        for (int j = 0; j < 8; ++j) s += c2p[tid][j];
        sc2d[tid] = s;
        sc2f[tid] = (float)s;
    }

    // ---- main: wave = tile (32 px), full K = 256 (16 steps of 16 ch) ----
    const int hl2  = (lane >> 5) & 1;              // k-subchunk select
    const int pp   = blockIdx.x * 128 + wv * 32 + (lane & 31);
    const int hw   = pp & (HW - 1);
    const int b    = pp >> 13;

    const float* __restrict__ fp = feat + (size_t)b * C * HW + hw;
    const int bidx = min(lane & 31, 18) * CPAD + hl2 * 8;   // B-frag LDS base

    f32x16 acc;
    #pragma unroll
    for (int r = 0; r < 16; ++r) acc[r] = 0.f;

    #pragma unroll
    for (int s = 0; s < 16; ++s) {                 // 16 K-steps of 16 channels
        const int cb = s * 16 + hl2 * 8;
        float fv[8];
        #pragma unroll
        for (int j = 0; j < 8; ++j)
            fv[j] = fp[(size_t)(cb + j) * HW];     // coalesced over lanes 0-31

        union { unsigned u[4]; bf16x8 v; } ah, al, bh, bl;
        #pragma unroll
        for (int j = 0; j < 4; ++j) {
            const unsigned u0 = __float_as_uint(fv[2*j]);
            const unsigned u1 = __float_as_uint(fv[2*j+1]);
            ah.u[j] = (u0 >> 16) | (u1 & 0xffff0000u);           // hi (truncate)
            const float r0 = fv[2*j]   - __uint_as_float(u0 & 0xffff0000u);
            const float r1 = fv[2*j+1] - __uint_as_float(u1 & 0xffff0000u);
            al.u[j] = (__float_as_uint(r0) >> 16)
                    | (__float_as_uint(r1) & 0xffff0000u);       // lo (truncate)
        }
        bh.v = *(const bf16x8*)&chi[bidx + s * 16];
        bl.v = *(const bf16x8*)&clo[bidx + s * 16];

        acc = __builtin_amdgcn_mfma_f32_32x32x16_bf16(ah.v, bh.v, acc, 0, 0, 0);
        acc = __builtin_amdgcn_mfma_f32_32x32x16_bf16(ah.v, bl.v, acc, 0, 0, 0);
        acc = __builtin_amdgcn_mfma_f32_32x32x16_bf16(al.v, bh.v, acc, 0, 0, 0);
    }

    // dump acc: element (reg, lane) = D[px=(reg&3)+8(reg>>2)+4(lane>>5)][k=lane&31]
    {
        float* dst = &dbuf[wv][0][hl2 * 32 + (lane & 31)];
        #pragma unroll
        for (int r = 0; r < 16; ++r) dst[r * DPAD] = acc[r];
    }
    __syncthreads();

    // ---- epilogue: waves 0+1, each owns 64 px (R8 pattern, disjoint ballots) ----
    if (tid < 128) {
        const int el  = tid & 63;          // lane within epilogue wave
        const int ep  = tid;               // pixel index within block: 0..127
        const int tl  = ep >> 5, px = ep & 31;
        const int h   = (px >> 2) & 1;
        const int reg = (px & 3) | ((px >> 3) << 2);
        const int bse = h * 32;

        const int ppx = blockIdx.x * 128 + ep;
        const int phw = ppx & (HW - 1);
        const int pb  = ppx >> 13;

        float d[K];
        #pragma unroll
        for (int k = 0; k < K; ++k)
            d[k] = sc2f[k] - 2.0f * dbuf[tl][reg][bse + k];

        int best = 0; float m1 = d[0];
        #pragma unroll
        for (int k = 1; k < K; ++k) if (d[k] < m1) { m1 = d[k]; best = k; }

        unsigned cmask = 0u;
        #pragma unroll
        for (int k = 0; k < K; ++k) if (d[k] - m1 < TAU) cmask |= (1u << k);

        // cooperative exact-f64 resolve of flagged pixels (proven, R8)
        const bool need = (cmask & (cmask - 1)) != 0u;
        unsigned long long ball = __ballot(need);
        while (ball) {
            const int sx = (int)__builtin_ctzll(ball);   // lowest flagged lane
            ball &= ball - 1;
            const unsigned pm  = __shfl(cmask, sx, 64);
            const int      fhw = __shfl(phw,   sx, 64);
            const int      fb  = __shfl(pb,    sx, 64);
            const float* __restrict__ fcol = feat + (size_t)fb * C * HW + fhw;

            const int c0 = el << 2;                      // channels 4l..4l+3
            double pf[4];
            #pragma unroll
            for (int j = 0; j < 4; ++j)
                pf[j] = (double)fcol[(size_t)(c0 + j) * HW];

            double bd = 1e300; int bi = 0;
            unsigned mm = pm;
            while (mm) {                      // ascending k, strict < tie-break
                const int k = (int)__builtin_ctz(mm);
                mm &= mm - 1;
                const float* __restrict__ ck = cent + (size_t)k * C + c0;
                double s = 0.0;
                #pragma unroll
                for (int j = 0; j < 4; ++j)
                    s = fma(pf[j], (double)ck[j], s);
                #pragma unroll
                for (int off = 1; off < 64; off <<= 1)
                    s += __shfl_xor(s, off, 64);
                const double dk = sc2d[k] - 2.0 * s;
                if (dk < bd) { bd = dk; bi = k; }
            }
            if (el == sx) best = bi;          // all lanes agree on bi
        }

        // write the 8x8 nearest-upsampled block
        const int w  = phw & (WF - 1);
        const int hh = phw >> 7;
        int4 v = make_int4(best, best, best, best);
        int* __restrict__ ob = out + (size_t)map * (BB * HL * WL)
                                   + (size_t)pb * (HL * WL)
                                   + (size_t)(hh * 8) * WL + (size_t)(w * 8);
        #pragma unroll
        for (int r = 0; r < 8; ++r) {
            *(int4*)(ob + (size_t)r * WL)     = v;
            *(int4*)(ob + (size_t)r * WL + 4) = v;
        }
    }
}

extern "C" void kernel_launch(void* const* d_in, const int* in_sizes, int n_in,
                              void* d_out, int out_size, void* d_ws, size_t ws_size,
                              hipStream_t stream) {
    const float* feature_s2t     = (const float*)d_in[0];
    const float* feature_target  = (const float*)d_in[1];
    // d_in[2], d_in[3]: labels — only shapes matter, unused
    const float* centroid_s2t    = (const float*)d_in[4];
    const float* centroid_target = (const float*)d_in[5];
    int* out = (int*)d_out;

    dim3 grid(32768 / 128, 2);   // (256, 2) -> 512 blocks, 4/CU
    dim3 block(256);
    hipLaunchKernelGGL(centroid_mask_kernel, grid, block, 0, stream,
                       feature_s2t, feature_target,
                       centroid_target, centroid_s2t, out);
}